// Round 3
// baseline (2877.690 us; speedup 1.0000x reference)
//
#include <hip/hip_runtime.h>
#include <hip/hip_bf16.h>
#include <math.h>

// Dims (fixed by the problem)
#define Bd 32
#define Sd 256
#define Ld 24
#define Ed 300
#define Hd 256
#define Td 16
#define Dd 256
#define EP 320   // E padded to multiple of 32

using short8 = __attribute__((ext_vector_type(8))) short;
using f32x4  = __attribute__((ext_vector_type(4))) float;

__device__ __forceinline__ float bl16(unsigned int p) {
  union { unsigned int i; float f; } v; v.i = p << 16; return v.f;
}
__device__ __forceinline__ float bh16(unsigned int p) {
  union { unsigned int i; float f; } v; v.i = p & 0xffff0000u; return v.f;
}
__device__ __forceinline__ float sigm(float x) { return 1.f / (1.f + expf(-x)); }

// ---------------------------------------------------------------------------
// 1. sentence means: A_pad[r][k] = bf16(mean_w emb[word_ids[r][w]][k]), k<300, else 0
// grid 8192, block 320. emb is FLOAT32.
__global__ void sent_means_kernel(const int* __restrict__ wids,
                                  const float* __restrict__ emb,
                                  __hip_bfloat16* __restrict__ apad) {
  int r = blockIdx.x;
  __shared__ int ids[Ld];
  int tid = threadIdx.x;
  if (tid < Ld) ids[tid] = wids[r * Ld + tid];
  __syncthreads();
  float acc = 0.f;
  if (tid < Ed) {
#pragma unroll
    for (int w = 0; w < Ld; ++w) acc += emb[(size_t)ids[w] * Ed + tid];
    acc *= (1.f / 24.f);
  }
  apad[r * EP + tid] = __float2bfloat16(tid < Ed ? acc : 0.f);
}

// ---------------------------------------------------------------------------
// 2. weight prep (all sources FLOAT32 -> bf16 for MFMA)
__global__ void pad_wih_kernel(const float* __restrict__ src,
                               __hip_bfloat16* __restrict__ dst) {
  int i = blockIdx.x * 256 + threadIdx.x;   // 768*320
  if (i >= 768 * EP) return;
  int n = i / EP, k = i % EP;
  dst[i] = __float2bfloat16(k < Ed ? src[n * Ed + k] : 0.f);
}
__global__ void f2bf_kernel(const float* __restrict__ src,
                            __hip_bfloat16* __restrict__ dst, int n) {
  int i = blockIdx.x * 256 + threadIdx.x;
  if (i < n) dst[i] = __float2bfloat16(src[i]);
}
__global__ void transpose_att_kernel(const float* __restrict__ src,
                                     __hip_bfloat16* __restrict__ dst) {
  int i = blockIdx.x * 256 + threadIdx.x;   // 1024*1024: dst[n][k] = src[k][n]
  int n = i >> 10, k = i & 1023;
  dst[i] = __float2bfloat16(src[k * 1024 + n]);
}
__global__ void transpose_dna_kernel(const float* __restrict__ src,
                                     __hip_bfloat16* __restrict__ dst) {
  int i = blockIdx.x * 256 + threadIdx.x;   // 256*1024: dst[n][k] = src[k][n]
  int n = i >> 10, k = i & 1023;
  dst[i] = __float2bfloat16(src[k * Dd + n]);
}

// ---------------------------------------------------------------------------
// 3. MFMA GEMM: C[M,N] = A[M,K] @ W[N,K]^T (+bias[n]); A,W bf16 row-major, C fp32.
// N % 64 == 0, K % 32 == 0; M arbitrary (loads clamped, stores masked).
__global__ __launch_bounds__(256) void gemm_xwt_kernel(
    const __hip_bfloat16* __restrict__ A, int lda,
    const __hip_bfloat16* __restrict__ W, int ldw,
    float* __restrict__ C, int ldc,
    int M, int N, int K,
    const float* __restrict__ bias) {
  __shared__ unsigned short la[64][32];
  __shared__ unsigned short lb[64][32];
  const int tid = threadIdx.x;
  const int m0 = blockIdx.x * 64, n0 = blockIdx.y * 64;
  const int lane = tid & 63, wid = tid >> 6;
  const int wm = (wid >> 1) * 32, wn = (wid & 1) * 32;
  const int lrow = tid >> 2, lcol = (tid & 3) * 8;
  f32x4 acc00 = {0.f, 0.f, 0.f, 0.f}, acc01 = {0.f, 0.f, 0.f, 0.f};
  f32x4 acc10 = {0.f, 0.f, 0.f, 0.f}, acc11 = {0.f, 0.f, 0.f, 0.f};
  int arow = m0 + lrow; if (arow > M - 1) arow = M - 1;
  const int brow = n0 + lrow;
  const int fr = lane & 15, fq = (lane >> 4) * 8;
  for (int k0 = 0; k0 < K; k0 += 32) {
    uint4 av = *(const uint4*)(A + (size_t)arow * lda + k0 + lcol);
    uint4 bv = *(const uint4*)(W + (size_t)brow * ldw + k0 + lcol);
    *(uint4*)(&la[lrow][lcol]) = av;
    *(uint4*)(&lb[lrow][lcol]) = bv;
    __syncthreads();
    short8 a0 = *(const short8*)(&la[wm + fr][fq]);
    short8 a1 = *(const short8*)(&la[wm + 16 + fr][fq]);
    short8 b0 = *(const short8*)(&lb[wn + fr][fq]);
    short8 b1 = *(const short8*)(&lb[wn + 16 + fr][fq]);
    acc00 = __builtin_amdgcn_mfma_f32_16x16x32_bf16(a0, b0, acc00, 0, 0, 0);
    acc01 = __builtin_amdgcn_mfma_f32_16x16x32_bf16(a0, b1, acc01, 0, 0, 0);
    acc10 = __builtin_amdgcn_mfma_f32_16x16x32_bf16(a1, b0, acc10, 0, 0, 0);
    acc11 = __builtin_amdgcn_mfma_f32_16x16x32_bf16(a1, b1, acc11, 0, 0, 0);
    __syncthreads();
  }
  const int rq = (lane >> 4) * 4;
  f32x4 accs[2][2] = {{acc00, acc01}, {acc10, acc11}};
  for (int i = 0; i < 2; ++i)
    for (int j = 0; j < 2; ++j) {
      int n = n0 + wn + j * 16 + fr;
      float bv = bias ? bias[n] : 0.f;
      for (int r2 = 0; r2 < 4; ++r2) {
        int m = m0 + wm + i * 16 + rq + r2;
        if (m < M) C[(size_t)m * ldc + n] = accs[i][j][r2] + bv;
      }
    }
}

// ---------------------------------------------------------------------------
// 4. GRU recurrence. grid 64 (dir = blk>>5, b = blk&31), block 768.
// Thread j computes gh_j = bhh[j] + h . Whh[j,:]; gates split r/z/n by j range.
// Whh pre-converted to bf16 (L2-resident stream); h and math in fp32.
__global__ __launch_bounds__(768) void gru_kernel(
    const float* __restrict__ gi_f, const float* __restrict__ gi_b,
    const __hip_bfloat16* __restrict__ whh_f, const __hip_bfloat16* __restrict__ whh_b,
    const float* __restrict__ bhh_f, const float* __restrict__ bhh_b,
    float* __restrict__ sent_rep, __hip_bfloat16* __restrict__ sent_rep_bf,
    float* __restrict__ hT_f, float* __restrict__ hT_b) {
  __shared__ float h[Hd];
  __shared__ float rb[Hd];
  __shared__ float zb[Hd];
  const int blk = blockIdx.x;
  const int dir = blk >> 5;
  const int b = blk & 31;
  const int j = threadIdx.x;
  const float* gi = dir ? gi_b : gi_f;
  const __hip_bfloat16* whh = dir ? whh_b : whh_f;
  const float bhh_j = (dir ? bhh_b : bhh_f)[j];
  if (j < Hd) h[j] = 0.f;
  __syncthreads();
  const uint4* w8 = (const uint4*)(whh + j * Hd);
  const int d = j - 512;
  for (int t = 0; t < Sd; ++t) {
    const int s = dir ? (Sd - 1 - t) : t;
    const float gi_v = gi[((b << 8) + s) * 768 + j];
    float acc = bhh_j;
    const float4* h4 = (const float4*)h;
#pragma unroll
    for (int c = 0; c < 32; ++c) {
      uint4 w = w8[c];
      float4 ha = h4[2 * c];
      float4 hb = h4[2 * c + 1];
      acc += bl16(w.x) * ha.x + bh16(w.x) * ha.y + bl16(w.y) * ha.z + bh16(w.y) * ha.w;
      acc += bl16(w.z) * hb.x + bh16(w.z) * hb.y + bl16(w.w) * hb.z + bh16(w.w) * hb.w;
    }
    if (j < 256) {
      rb[j] = sigm(gi_v + acc);
    } else if (j < 512) {
      zb[j - 256] = sigm(gi_v + acc);
    }
    __syncthreads();
    if (j >= 512) {
      float rr = rb[d], zz = zb[d];
      float nn = tanhf(gi_v + rr * acc);
      float hn = (1.f - zz) * nn + zz * h[d];
      h[d] = hn;
      const size_t row = (size_t)((b << 8) + s);
      const int col = dir ? (Hd + d) : d;
      sent_rep[row * 512 + col] = hn;
      sent_rep_bf[row * 512 + col] = __float2bfloat16(hn);
    }
    __syncthreads();
  }
  if (j < Hd) (dir ? hT_b : hT_f)[b * Hd + j] = h[j];
}

// ---------------------------------------------------------------------------
// 5. doc_vec per torch view(B,2H) on stacked [2,B,H]. grid 32, block 512.
__global__ void docvec_kernel(const float* __restrict__ hTf, const float* __restrict__ hTb,
                              __hip_bfloat16* __restrict__ dv) {
  int b = blockIdx.x, jj = threadIdx.x;
  int idx = b * 512 + jj;
  int dsel = idx >> 13;            // /8192
  int rem = idx & 8191;
  int bp = rem >> 8, hp = rem & 255;
  float v = (dsel ? hTb : hTf)[bp * Hd + hp];
  dv[idx] = __float2bfloat16(v);
}

// 6. topic_mat via boundary differencing. grid 512 (b*16+t), block 256.
__global__ void topic_kernel(const int* __restrict__ tse, const float* __restrict__ sent_rep,
                             __hip_bfloat16* __restrict__ topic_bf) {
  int bt = blockIdx.x;
  int b = bt >> 4;
  int st = tse[bt * 2], en = tse[bt * 2 + 1];   // 1-indexed
  int dd = threadIdx.x;
  auto pad = [&](int i, int col) -> float {
    if (i < 1 || i > Sd) return 0.f;
    return sent_rep[((size_t)((b << 8) + (i - 1))) * 512 + col];
  };
  float fwd = pad(en, dd) - pad(st - 1, dd);
  float bwd = pad(st, Hd + dd) - pad(en + 1, Hd + dd);
  topic_bf[(size_t)bt * 512 + dd] = __float2bfloat16(fwd);
  topic_bf[(size_t)bt * 512 + Hd + dd] = __float2bfloat16(bwd);
}

// ---------------------------------------------------------------------------
// 7. attention scores. grid 8192 (b*256+s), block 256.
// doc_sc = sum_n tanh(P[b,n]+Q[r,n]) v[n]; top_sc = sum_n tanh(R[b,tsel,n]+Q[r,n]) v[n]
__global__ void scores_kernel(const float* __restrict__ P, const float* __restrict__ R,
                              const float* __restrict__ Q, const float* __restrict__ v_att,
                              const int* __restrict__ tse,
                              float* __restrict__ dsc, float* __restrict__ tsc) {
  int r = blockIdx.x;
  int b = r >> 8, s = r & 255;
  int tid = threadIdx.x;
  int tsel = Td - 1;
  for (int t = 0; t < Td; ++t) {
    if (tse[(b * Td + t) * 2 + 1] >= s + 1) { tsel = t; break; }
  }
  const float* q = Q + (size_t)r * 1024;
  const float* p = P + (size_t)b * 1024;
  const float* rr = R + (size_t)(b * Td + tsel) * 1024;
  float accd = 0.f, acct = 0.f;
  for (int n = tid; n < 1024; n += 256) {
    float qv = q[n];
    float vv = v_att[n];
    accd += tanhf(p[n] + qv) * vv;
    acct += tanhf(rr[n] + qv) * vv;
  }
  __shared__ float s1[256], s2[256];
  s1[tid] = accd; s2[tid] = acct;
  __syncthreads();
  for (int off = 128; off > 0; off >>= 1) {
    if (tid < off) { s1[tid] += s1[tid + off]; s2[tid] += s2[tid + off]; }
    __syncthreads();
  }
  if (tid == 0) { dsc[r] = s1[0]; tsc[r] = s2[0]; }
}

// 8. softmax over s per batch (both score sets). grid 32, block 256.
__global__ void softmax_kernel(const float* __restrict__ dsc, const float* __restrict__ tsc,
                               float* __restrict__ dw, float* __restrict__ tw) {
  int b = blockIdx.x, s = threadIdx.x;
  __shared__ float red[256];
  for (int which = 0; which < 2; ++which) {
    const float* src = which ? tsc : dsc;
    float v = src[b * Sd + s];
    red[s] = v; __syncthreads();
    for (int off = 128; off > 0; off >>= 1) {
      if (s < off) red[s] = fmaxf(red[s], red[s + off]);
      __syncthreads();
    }
    float m = red[0]; __syncthreads();
    float e = expf(v - m);
    red[s] = e; __syncthreads();
    for (int off = 128; off > 0; off >>= 1) {
      if (s < off) red[s] += red[s + off];
      __syncthreads();
    }
    float sum = red[0]; __syncthreads();
    (which ? tw : dw)[b * Sd + s] = e / sum;
  }
}

// 9. final head. grid 8192, block 256. OUTPUT IS FP32.
// logit = b_out + sum_d relu(U[r,d] + dw*dvd[b,d] + tw*tvd[b,tsel,d] + b_dna[d]) * W_out[d]
__global__ void final_kernel(const float* __restrict__ U, const float* __restrict__ dvd,
                             const float* __restrict__ tvd, const float* __restrict__ dw,
                             const float* __restrict__ tw, const float* __restrict__ b_dna,
                             const float* __restrict__ w_out,
                             const float* __restrict__ b_out,
                             const int* __restrict__ tse, float* __restrict__ out) {
  int r = blockIdx.x;
  int b = r >> 8, s = r & 255;
  int dd = threadIdx.x;
  int tsel = Td - 1;
  for (int t = 0; t < Td; ++t) {
    if (tse[(b * Td + t) * 2 + 1] >= s + 1) { tsel = t; break; }
  }
  float wdv = dw[b * Sd + s], wtv = tw[b * Sd + s];
  float x = U[(size_t)r * Dd + dd] + wdv * dvd[b * Dd + dd] +
            wtv * tvd[(size_t)(b * Td + tsel) * Dd + dd] + b_dna[dd];
  x = fmaxf(x, 0.f);
  float term = x * w_out[dd];
  __shared__ float red[256];
  red[dd] = term; __syncthreads();
  for (int off = 128; off > 0; off >>= 1) {
    if (dd < off) red[dd] += red[dd + off];
    __syncthreads();
  }
  if (dd == 0) out[r] = red[0] + b_out[0];
}

// ---------------------------------------------------------------------------
static void launch_gemm(const __hip_bfloat16* A, int lda, const __hip_bfloat16* W, int ldw,
                        float* C, int ldc, int M, int N, int K,
                        const float* bias, hipStream_t stream) {
  dim3 grid((M + 63) / 64, N / 64);
  gemm_xwt_kernel<<<grid, 256, 0, stream>>>(A, lda, W, ldw, C, ldc, M, N, K, bias);
}

extern "C" void kernel_launch(void* const* d_in, const int* in_sizes, int n_in,
                              void* d_out, int out_size, void* d_ws, size_t ws_size,
                              hipStream_t stream) {
  const int* word_ids = (const int*)d_in[0];
  const int* tse      = (const int*)d_in[1];
  const float* emb   = (const float*)d_in[2];
  const float* wih_f = (const float*)d_in[3];
  const float* whh_f = (const float*)d_in[4];
  const float* bih_f = (const float*)d_in[5];
  const float* bhh_f = (const float*)d_in[6];
  const float* wih_b = (const float*)d_in[7];
  const float* whh_b = (const float*)d_in[8];
  const float* bih_b = (const float*)d_in[9];
  const float* bhh_b = (const float*)d_in[10];
  const float* w_att = (const float*)d_in[11];
  const float* v_att = (const float*)d_in[12];
  const float* w_dna = (const float*)d_in[13];
  const float* b_dna = (const float*)d_in[14];
  const float* w_out = (const float*)d_in[15];
  const float* b_out = (const float*)d_in[16];
  float* out = (float*)d_out;
  char* ws = (char*)d_ws;

  const int M = Bd * Sd;  // 8192

  // workspace layout (bytes)
  size_t off = 0;
  auto alloc = [&](size_t sz) { size_t o = off; off += (sz + 255) & ~(size_t)255; return o; };
  size_t o_svbf   = alloc((size_t)M * EP * 2);          // A_pad bf16 [8192,320]
  size_t o_wpadf  = alloc((size_t)768 * EP * 2);
  size_t o_wpadb  = alloc((size_t)768 * EP * 2);
  size_t o_whhbf  = alloc((size_t)768 * Hd * 2 * 2);    // whh f+b bf16
  size_t o_wattT  = alloc((size_t)1024 * 1024 * 2);     // WattT[n][k] bf16
  size_t o_wdnaT  = alloc((size_t)Dd * 1024 * 2);       // WdnaT[n][k] bf16
  size_t o_hTf    = alloc((size_t)Bd * Hd * 4);
  size_t o_hTb    = alloc((size_t)Bd * Hd * 4);
  size_t o_dvbf   = alloc((size_t)Bd * 512 * 2);        // doc_vec bf16
  size_t o_topbf  = alloc((size_t)Bd * Td * 512 * 2);   // topic_mat bf16
  size_t o_P      = alloc((size_t)Bd * 1024 * 4);
  size_t o_R      = alloc((size_t)Bd * Td * 1024 * 4);
  size_t o_dvd    = alloc((size_t)Bd * Dd * 4);
  size_t o_tvd    = alloc((size_t)Bd * Td * Dd * 4);
  size_t o_dsc    = alloc((size_t)Bd * Sd * 4);
  size_t o_tsc    = alloc((size_t)Bd * Sd * 4);
  size_t o_dw     = alloc((size_t)Bd * Sd * 4);
  size_t o_tw     = alloc((size_t)Bd * Sd * 4);
  size_t o_srep32 = alloc((size_t)M * 512 * 4);         // sent_rep fp32
  size_t o_srepbf = alloc((size_t)M * 512 * 2);         // sent_rep bf16
  size_t o_gif    = alloc((size_t)M * 768 * 4);         // gi fwd fp32
  size_t o_gib    = alloc((size_t)M * 768 * 4);         // gi bwd fp32
  // Q [8192,1024] f32 and U [8192,256] f32 overlay the dead gi region after GRU
  size_t o_Q = o_gif;
  size_t o_U = o_gif + (size_t)M * 1024 * 4;
  (void)ws_size;

  __hip_bfloat16* svbf   = (__hip_bfloat16*)(ws + o_svbf);
  __hip_bfloat16* wpadf  = (__hip_bfloat16*)(ws + o_wpadf);
  __hip_bfloat16* wpadb  = (__hip_bfloat16*)(ws + o_wpadb);
  __hip_bfloat16* whhbf_f = (__hip_bfloat16*)(ws + o_whhbf);
  __hip_bfloat16* whhbf_b = whhbf_f + 768 * Hd;
  __hip_bfloat16* wattT  = (__hip_bfloat16*)(ws + o_wattT);
  __hip_bfloat16* wdnaT  = (__hip_bfloat16*)(ws + o_wdnaT);
  float* hTf = (float*)(ws + o_hTf);
  float* hTb = (float*)(ws + o_hTb);
  __hip_bfloat16* dvbf  = (__hip_bfloat16*)(ws + o_dvbf);
  __hip_bfloat16* topbf = (__hip_bfloat16*)(ws + o_topbf);
  float* P   = (float*)(ws + o_P);
  float* R   = (float*)(ws + o_R);
  float* dvd = (float*)(ws + o_dvd);
  float* tvd = (float*)(ws + o_tvd);
  float* dsc = (float*)(ws + o_dsc);
  float* tsc = (float*)(ws + o_tsc);
  float* dw  = (float*)(ws + o_dw);
  float* tw  = (float*)(ws + o_tw);
  float* srep32 = (float*)(ws + o_srep32);
  __hip_bfloat16* srepbf = (__hip_bfloat16*)(ws + o_srepbf);
  float* gif = (float*)(ws + o_gif);
  float* gib = (float*)(ws + o_gib);
  float* Q = (float*)(ws + o_Q);
  float* U = (float*)(ws + o_U);

  // 1. sentence means -> padded bf16 activations
  sent_means_kernel<<<M, EP, 0, stream>>>(word_ids, emb, svbf);
  // 2. weight prep (fp32 -> bf16)
  pad_wih_kernel<<<(768 * EP) / 256, 256, 0, stream>>>(wih_f, wpadf);
  pad_wih_kernel<<<(768 * EP) / 256, 256, 0, stream>>>(wih_b, wpadb);
  f2bf_kernel<<<(768 * Hd) / 256, 256, 0, stream>>>(whh_f, whhbf_f, 768 * Hd);
  f2bf_kernel<<<(768 * Hd) / 256, 256, 0, stream>>>(whh_b, whhbf_b, 768 * Hd);
  transpose_att_kernel<<<(1024 * 1024) / 256, 256, 0, stream>>>(w_att, wattT);
  transpose_dna_kernel<<<(Dd * 1024) / 256, 256, 0, stream>>>(w_dna, wdnaT);
  // 3. input projections gi = sv @ Wih^T + bih
  launch_gemm(svbf, EP, wpadf, EP, gif, 768, M, 768, EP, bih_f, stream);
  launch_gemm(svbf, EP, wpadb, EP, gib, 768, M, 768, EP, bih_b, stream);
  // 4. bidirectional GRU recurrence
  gru_kernel<<<64, 768, 0, stream>>>(gif, gib, whhbf_f, whhbf_b, bhh_f, bhh_b,
                                     srep32, srepbf, hTf, hTb);
  // 5/6. doc_vec + topic_mat
  docvec_kernel<<<Bd, 512, 0, stream>>>(hTf, hTb, dvbf);
  topic_kernel<<<Bd * Td, 256, 0, stream>>>(tse, srep32, topbf);
  // 7. attention/dense GEMMs
  //   Q = sent_rep @ W_att[512:, :]   (k-offset 512 into wattT rows)
  launch_gemm(srepbf, 512, wattT + 512, 1024, Q, 1024, M, 1024, 512, nullptr, stream);
  //   P = doc_vec @ W_att[:512, :]
  launch_gemm(dvbf, 512, wattT, 1024, P, 1024, Bd, 1024, 512, nullptr, stream);
  //   R = topic_mat @ W_att[:512, :]
  launch_gemm(topbf, 512, wattT, 1024, R, 1024, Bd * Td, 1024, 512, nullptr, stream);
  //   U = sent_rep @ W_dna[:512, :]
  launch_gemm(srepbf, 512, wdnaT, 1024, U, Dd, M, Dd, 512, nullptr, stream);
  //   dvd = doc_vec @ W_dna[512:, :]
  launch_gemm(dvbf, 512, wdnaT + 512, 1024, dvd, Dd, Bd, Dd, 512, nullptr, stream);
  //   tvd = topic_mat @ W_dna[512:, :]
  launch_gemm(topbf, 512, wdnaT + 512, 1024, tvd, Dd, Bd * Td, Dd, 512, nullptr, stream);
  // 8. scores + softmax
  scores_kernel<<<M, 256, 0, stream>>>(P, R, Q, v_att, tse, dsc, tsc);
  softmax_kernel<<<Bd, 256, 0, stream>>>(dsc, tsc, dw, tw);
  // 9. fused dense head -> logits (fp32)
  final_kernel<<<M, 256, 0, stream>>>(U, dvd, tvd, dw, tw, b_dna, w_out, b_out, tse, out);
}

// Round 4
// 2877.575 us; speedup vs baseline: 1.0000x; 1.0000x over previous
//
#include <hip/hip_runtime.h>
#include <hip/hip_bf16.h>
#include <math.h>

// Dims (fixed by the problem)
#define Bd 32
#define Sd 256
#define Ld 24
#define Ed 300
#define Hd 256
#define Td 16
#define Dd 256
#define EP 320   // E padded to multiple of 32

using short8 = __attribute__((ext_vector_type(8))) short;
using f32x4  = __attribute__((ext_vector_type(4))) float;

__device__ __forceinline__ float bl16(unsigned int p) {
  union { unsigned int i; float f; } v; v.i = p << 16; return v.f;
}
__device__ __forceinline__ float bh16(unsigned int p) {
  union { unsigned int i; float f; } v; v.i = p & 0xffff0000u; return v.f;
}
__device__ __forceinline__ float sigm(float x) { return 1.f / (1.f + expf(-x)); }

// ---------------------------------------------------------------------------
// 1. sentence means: A_pad[r][k] = bf16(mean_w emb[word_ids[r][w]][k]), k<300, else 0
// grid 8192, block 320. emb is FLOAT32.
__global__ void sent_means_kernel(const int* __restrict__ wids,
                                  const float* __restrict__ emb,
                                  __hip_bfloat16* __restrict__ apad) {
  int r = blockIdx.x;
  __shared__ int ids[Ld];
  int tid = threadIdx.x;
  if (tid < Ld) ids[tid] = wids[r * Ld + tid];
  __syncthreads();
  float acc = 0.f;
  if (tid < Ed) {
#pragma unroll
    for (int w = 0; w < Ld; ++w) acc += emb[(size_t)ids[w] * Ed + tid];
    acc *= (1.f / 24.f);
  }
  apad[r * EP + tid] = __float2bfloat16(tid < Ed ? acc : 0.f);
}

// ---------------------------------------------------------------------------
// 2. weight prep (all sources FLOAT32 -> bf16 for MFMA)
__global__ void pad_wih_kernel(const float* __restrict__ src,
                               __hip_bfloat16* __restrict__ dst) {
  int i = blockIdx.x * 256 + threadIdx.x;   // 768*320
  if (i >= 768 * EP) return;
  int n = i / EP, k = i % EP;
  dst[i] = __float2bfloat16(k < Ed ? src[n * Ed + k] : 0.f);
}
// Whh [768,256] fp32 -> interleaved bf16 layout [kb=k/8][j][k%8] so that
// thread j's 16B load of k-block kb sits at ((kb*768+j)*16) bytes: lane-adjacent
// j => adjacent 16B lines => fully coalesced 1KB wave loads in the GRU loop.
__global__ void whh_interleave_kernel(const float* __restrict__ src,
                                      __hip_bfloat16* __restrict__ dst) {
  int i = blockIdx.x * 256 + threadIdx.x;   // 768*256
  if (i >= 768 * Hd) return;
  int j = i >> 8, k = i & 255;
  int kb = k >> 3, ki = k & 7;
  dst[((size_t)kb * 768 + j) * 8 + ki] = __float2bfloat16(src[i]);
}
__global__ void transpose_att_kernel(const float* __restrict__ src,
                                     __hip_bfloat16* __restrict__ dst) {
  int i = blockIdx.x * 256 + threadIdx.x;   // 1024*1024: dst[n][k] = src[k][n]
  int n = i >> 10, k = i & 1023;
  dst[i] = __float2bfloat16(src[k * 1024 + n]);
}
__global__ void transpose_dna_kernel(const float* __restrict__ src,
                                     __hip_bfloat16* __restrict__ dst) {
  int i = blockIdx.x * 256 + threadIdx.x;   // 256*1024: dst[n][k] = src[k][n]
  int n = i >> 10, k = i & 1023;
  dst[i] = __float2bfloat16(src[k * Dd + n]);
}

// ---------------------------------------------------------------------------
// 3. MFMA GEMM: C[M,N] = A[M,K] @ W[N,K]^T (+bias[n]); A,W bf16 row-major, C fp32.
// N % 64 == 0, K % 32 == 0; M arbitrary (loads clamped, stores masked).
__global__ __launch_bounds__(256) void gemm_xwt_kernel(
    const __hip_bfloat16* __restrict__ A, int lda,
    const __hip_bfloat16* __restrict__ W, int ldw,
    float* __restrict__ C, int ldc,
    int M, int N, int K,
    const float* __restrict__ bias) {
  __shared__ unsigned short la[64][32];
  __shared__ unsigned short lb[64][32];
  const int tid = threadIdx.x;
  const int m0 = blockIdx.x * 64, n0 = blockIdx.y * 64;
  const int lane = tid & 63, wid = tid >> 6;
  const int wm = (wid >> 1) * 32, wn = (wid & 1) * 32;
  const int lrow = tid >> 2, lcol = (tid & 3) * 8;
  f32x4 acc00 = {0.f, 0.f, 0.f, 0.f}, acc01 = {0.f, 0.f, 0.f, 0.f};
  f32x4 acc10 = {0.f, 0.f, 0.f, 0.f}, acc11 = {0.f, 0.f, 0.f, 0.f};
  int arow = m0 + lrow; if (arow > M - 1) arow = M - 1;
  const int brow = n0 + lrow;
  const int fr = lane & 15, fq = (lane >> 4) * 8;
  for (int k0 = 0; k0 < K; k0 += 32) {
    uint4 av = *(const uint4*)(A + (size_t)arow * lda + k0 + lcol);
    uint4 bv = *(const uint4*)(W + (size_t)brow * ldw + k0 + lcol);
    *(uint4*)(&la[lrow][lcol]) = av;
    *(uint4*)(&lb[lrow][lcol]) = bv;
    __syncthreads();
    short8 a0 = *(const short8*)(&la[wm + fr][fq]);
    short8 a1 = *(const short8*)(&la[wm + 16 + fr][fq]);
    short8 b0 = *(const short8*)(&lb[wn + fr][fq]);
    short8 b1 = *(const short8*)(&lb[wn + 16 + fr][fq]);
    acc00 = __builtin_amdgcn_mfma_f32_16x16x32_bf16(a0, b0, acc00, 0, 0, 0);
    acc01 = __builtin_amdgcn_mfma_f32_16x16x32_bf16(a0, b1, acc01, 0, 0, 0);
    acc10 = __builtin_amdgcn_mfma_f32_16x16x32_bf16(a1, b0, acc10, 0, 0, 0);
    acc11 = __builtin_amdgcn_mfma_f32_16x16x32_bf16(a1, b1, acc11, 0, 0, 0);
    __syncthreads();
  }
  const int rq = (lane >> 4) * 4;
  f32x4 accs[2][2] = {{acc00, acc01}, {acc10, acc11}};
  for (int i = 0; i < 2; ++i)
    for (int j = 0; j < 2; ++j) {
      int n = n0 + wn + j * 16 + fr;
      float bv = bias ? bias[n] : 0.f;
      for (int r2 = 0; r2 < 4; ++r2) {
        int m = m0 + wm + i * 16 + rq + r2;
        if (m < M) C[(size_t)m * ldc + n] = accs[i][j][r2] + bv;
      }
    }
}

// ---------------------------------------------------------------------------
// 4. GRU recurrence. grid 64 (dir = blk>>5, b = blk&31), block 768.
// Thread j computes gh_j = bhh[j] + h . Whh[j,:]; gates split r/z/n by j range.
// whh_il is the interleaved bf16 layout [kb][j][8] (coalesced 16B/lane loads).
__global__ __launch_bounds__(768) void gru_kernel(
    const float* __restrict__ gi_f, const float* __restrict__ gi_b,
    const __hip_bfloat16* __restrict__ whhil_f, const __hip_bfloat16* __restrict__ whhil_b,
    const float* __restrict__ bhh_f, const float* __restrict__ bhh_b,
    float* __restrict__ sent_rep, __hip_bfloat16* __restrict__ sent_rep_bf,
    float* __restrict__ hT_f, float* __restrict__ hT_b) {
  __shared__ float h[Hd];
  __shared__ float rb[Hd];
  __shared__ float zb[Hd];
  const int blk = blockIdx.x;
  const int dir = blk >> 5;
  const int b = blk & 31;
  const int j = threadIdx.x;
  const float* gi = dir ? gi_b : gi_f;
  const __hip_bfloat16* whh = dir ? whhil_b : whhil_f;
  const float bhh_j = (dir ? bhh_b : bhh_f)[j];
  if (j < Hd) h[j] = 0.f;
  __syncthreads();
  const uint4* w8 = (const uint4*)whh;   // w8[kb*768 + j] = 8 bf16 of row j, k=8kb..8kb+7
  const int d = j - 512;
  for (int t = 0; t < Sd; ++t) {
    const int s = dir ? (Sd - 1 - t) : t;
    const float gi_v = gi[((b << 8) + s) * 768 + j];
    float acc = bhh_j;
    const float4* h4 = (const float4*)h;
#pragma unroll
    for (int c = 0; c < 32; ++c) {
      uint4 w = w8[c * 768 + j];
      float4 ha = h4[2 * c];
      float4 hb = h4[2 * c + 1];
      acc += bl16(w.x) * ha.x + bh16(w.x) * ha.y + bl16(w.y) * ha.z + bh16(w.y) * ha.w;
      acc += bl16(w.z) * hb.x + bh16(w.z) * hb.y + bl16(w.w) * hb.z + bh16(w.w) * hb.w;
    }
    if (j < 256) {
      rb[j] = sigm(gi_v + acc);
    } else if (j < 512) {
      zb[j - 256] = sigm(gi_v + acc);
    }
    __syncthreads();
    if (j >= 512) {
      float rr = rb[d], zz = zb[d];
      float nn = tanhf(gi_v + rr * acc);
      float hn = (1.f - zz) * nn + zz * h[d];
      h[d] = hn;
      const size_t row = (size_t)((b << 8) + s);
      const int col = dir ? (Hd + d) : d;
      sent_rep[row * 512 + col] = hn;
      sent_rep_bf[row * 512 + col] = __float2bfloat16(hn);
    }
    __syncthreads();
  }
  if (j < Hd) (dir ? hT_b : hT_f)[b * Hd + j] = h[j];
}

// ---------------------------------------------------------------------------
// 5. doc_vec per torch view(B,2H) on stacked [2,B,H]. grid 32, block 512.
__global__ void docvec_kernel(const float* __restrict__ hTf, const float* __restrict__ hTb,
                              __hip_bfloat16* __restrict__ dv) {
  int b = blockIdx.x, jj = threadIdx.x;
  int idx = b * 512 + jj;
  int dsel = idx >> 13;            // /8192
  int rem = idx & 8191;
  int bp = rem >> 8, hp = rem & 255;
  float v = (dsel ? hTb : hTf)[bp * Hd + hp];
  dv[idx] = __float2bfloat16(v);
}

// 6. topic_mat via boundary differencing. grid 512 (b*16+t), block 256.
__global__ void topic_kernel(const int* __restrict__ tse, const float* __restrict__ sent_rep,
                             __hip_bfloat16* __restrict__ topic_bf) {
  int bt = blockIdx.x;
  int b = bt >> 4;
  int st = tse[bt * 2], en = tse[bt * 2 + 1];   // 1-indexed
  int dd = threadIdx.x;
  auto pad = [&](int i, int col) -> float {
    if (i < 1 || i > Sd) return 0.f;
    return sent_rep[((size_t)((b << 8) + (i - 1))) * 512 + col];
  };
  float fwd = pad(en, dd) - pad(st - 1, dd);
  float bwd = pad(st, Hd + dd) - pad(en + 1, Hd + dd);
  topic_bf[(size_t)bt * 512 + dd] = __float2bfloat16(fwd);
  topic_bf[(size_t)bt * 512 + Hd + dd] = __float2bfloat16(bwd);
}

// ---------------------------------------------------------------------------
// 7. attention scores. grid 8192 (b*256+s), block 256.
// doc_sc = sum_n tanh(P[b,n]+Q[r,n]) v[n]; top_sc = sum_n tanh(R[b,tsel,n]+Q[r,n]) v[n]
__global__ void scores_kernel(const float* __restrict__ P, const float* __restrict__ R,
                              const float* __restrict__ Q, const float* __restrict__ v_att,
                              const int* __restrict__ tse,
                              float* __restrict__ dsc, float* __restrict__ tsc) {
  int r = blockIdx.x;
  int b = r >> 8, s = r & 255;
  int tid = threadIdx.x;
  int tsel = Td - 1;
  for (int t = 0; t < Td; ++t) {
    if (tse[(b * Td + t) * 2 + 1] >= s + 1) { tsel = t; break; }
  }
  const float* q = Q + (size_t)r * 1024;
  const float* p = P + (size_t)b * 1024;
  const float* rr = R + (size_t)(b * Td + tsel) * 1024;
  float accd = 0.f, acct = 0.f;
  for (int n = tid; n < 1024; n += 256) {
    float qv = q[n];
    float vv = v_att[n];
    accd += tanhf(p[n] + qv) * vv;
    acct += tanhf(rr[n] + qv) * vv;
  }
  __shared__ float s1[256], s2[256];
  s1[tid] = accd; s2[tid] = acct;
  __syncthreads();
  for (int off = 128; off > 0; off >>= 1) {
    if (tid < off) { s1[tid] += s1[tid + off]; s2[tid] += s2[tid + off]; }
    __syncthreads();
  }
  if (tid == 0) { dsc[r] = s1[0]; tsc[r] = s2[0]; }
}

// 8. softmax over s per batch (both score sets). grid 32, block 256.
__global__ void softmax_kernel(const float* __restrict__ dsc, const float* __restrict__ tsc,
                               float* __restrict__ dw, float* __restrict__ tw) {
  int b = blockIdx.x, s = threadIdx.x;
  __shared__ float red[256];
  for (int which = 0; which < 2; ++which) {
    const float* src = which ? tsc : dsc;
    float v = src[b * Sd + s];
    red[s] = v; __syncthreads();
    for (int off = 128; off > 0; off >>= 1) {
      if (s < off) red[s] = fmaxf(red[s], red[s + off]);
      __syncthreads();
    }
    float m = red[0]; __syncthreads();
    float e = expf(v - m);
    red[s] = e; __syncthreads();
    for (int off = 128; off > 0; off >>= 1) {
      if (s < off) red[s] += red[s + off];
      __syncthreads();
    }
    float sum = red[0]; __syncthreads();
    (which ? tw : dw)[b * Sd + s] = e / sum;
  }
}

// 9. final head. grid 8192, block 256. OUTPUT IS FP32.
// logit = b_out + sum_d relu(U[r,d] + dw*dvd[b,d] + tw*tvd[b,tsel,d] + b_dna[d]) * W_out[d]
__global__ void final_kernel(const float* __restrict__ U, const float* __restrict__ dvd,
                             const float* __restrict__ tvd, const float* __restrict__ dw,
                             const float* __restrict__ tw, const float* __restrict__ b_dna,
                             const float* __restrict__ w_out,
                             const float* __restrict__ b_out,
                             const int* __restrict__ tse, float* __restrict__ out) {
  int r = blockIdx.x;
  int b = r >> 8, s = r & 255;
  int dd = threadIdx.x;
  int tsel = Td - 1;
  for (int t = 0; t < Td; ++t) {
    if (tse[(b * Td + t) * 2 + 1] >= s + 1) { tsel = t; break; }
  }
  float wdv = dw[b * Sd + s], wtv = tw[b * Sd + s];
  float x = U[(size_t)r * Dd + dd] + wdv * dvd[b * Dd + dd] +
            wtv * tvd[(size_t)(b * Td + tsel) * Dd + dd] + b_dna[dd];
  x = fmaxf(x, 0.f);
  float term = x * w_out[dd];
  __shared__ float red[256];
  red[dd] = term; __syncthreads();
  for (int off = 128; off > 0; off >>= 1) {
    if (dd < off) red[dd] += red[dd + off];
    __syncthreads();
  }
  if (dd == 0) out[r] = red[0] + b_out[0];
}

// ---------------------------------------------------------------------------
static void launch_gemm(const __hip_bfloat16* A, int lda, const __hip_bfloat16* W, int ldw,
                        float* C, int ldc, int M, int N, int K,
                        const float* bias, hipStream_t stream) {
  dim3 grid((M + 63) / 64, N / 64);
  gemm_xwt_kernel<<<grid, 256, 0, stream>>>(A, lda, W, ldw, C, ldc, M, N, K, bias);
}

extern "C" void kernel_launch(void* const* d_in, const int* in_sizes, int n_in,
                              void* d_out, int out_size, void* d_ws, size_t ws_size,
                              hipStream_t stream) {
  const int* word_ids = (const int*)d_in[0];
  const int* tse      = (const int*)d_in[1];
  const float* emb   = (const float*)d_in[2];
  const float* wih_f = (const float*)d_in[3];
  const float* whh_f = (const float*)d_in[4];
  const float* bih_f = (const float*)d_in[5];
  const float* bhh_f = (const float*)d_in[6];
  const float* wih_b = (const float*)d_in[7];
  const float* whh_b = (const float*)d_in[8];
  const float* bih_b = (const float*)d_in[9];
  const float* bhh_b = (const float*)d_in[10];
  const float* w_att = (const float*)d_in[11];
  const float* v_att = (const float*)d_in[12];
  const float* w_dna = (const float*)d_in[13];
  const float* b_dna = (const float*)d_in[14];
  const float* w_out = (const float*)d_in[15];
  const float* b_out = (const float*)d_in[16];
  float* out = (float*)d_out;
  char* ws = (char*)d_ws;

  const int M = Bd * Sd;  // 8192

  // workspace layout (bytes)
  size_t off = 0;
  auto alloc = [&](size_t sz) { size_t o = off; off += (sz + 255) & ~(size_t)255; return o; };
  size_t o_svbf   = alloc((size_t)M * EP * 2);          // A_pad bf16 [8192,320]
  size_t o_wpadf  = alloc((size_t)768 * EP * 2);
  size_t o_wpadb  = alloc((size_t)768 * EP * 2);
  size_t o_whhil  = alloc((size_t)768 * Hd * 2 * 2);    // whh f+b bf16 interleaved
  size_t o_wattT  = alloc((size_t)1024 * 1024 * 2);     // WattT[n][k] bf16
  size_t o_wdnaT  = alloc((size_t)Dd * 1024 * 2);       // WdnaT[n][k] bf16
  size_t o_hTf    = alloc((size_t)Bd * Hd * 4);
  size_t o_hTb    = alloc((size_t)Bd * Hd * 4);
  size_t o_dvbf   = alloc((size_t)Bd * 512 * 2);        // doc_vec bf16
  size_t o_topbf  = alloc((size_t)Bd * Td * 512 * 2);   // topic_mat bf16
  size_t o_P      = alloc((size_t)Bd * 1024 * 4);
  size_t o_R      = alloc((size_t)Bd * Td * 1024 * 4);
  size_t o_dvd    = alloc((size_t)Bd * Dd * 4);
  size_t o_tvd    = alloc((size_t)Bd * Td * Dd * 4);
  size_t o_dsc    = alloc((size_t)Bd * Sd * 4);
  size_t o_tsc    = alloc((size_t)Bd * Sd * 4);
  size_t o_dw     = alloc((size_t)Bd * Sd * 4);
  size_t o_tw     = alloc((size_t)Bd * Sd * 4);
  size_t o_srep32 = alloc((size_t)M * 512 * 4);         // sent_rep fp32
  size_t o_srepbf = alloc((size_t)M * 512 * 2);         // sent_rep bf16
  size_t o_gif    = alloc((size_t)M * 768 * 4);         // gi fwd fp32
  size_t o_gib    = alloc((size_t)M * 768 * 4);         // gi bwd fp32
  // Q [8192,1024] f32 and U [8192,256] f32 overlay the dead gi region after GRU
  size_t o_Q = o_gif;
  size_t o_U = o_gif + (size_t)M * 1024 * 4;
  (void)ws_size;

  __hip_bfloat16* svbf   = (__hip_bfloat16*)(ws + o_svbf);
  __hip_bfloat16* wpadf  = (__hip_bfloat16*)(ws + o_wpadf);
  __hip_bfloat16* wpadb  = (__hip_bfloat16*)(ws + o_wpadb);
  __hip_bfloat16* whhil_f = (__hip_bfloat16*)(ws + o_whhil);
  __hip_bfloat16* whhil_b = whhil_f + 768 * Hd;
  __hip_bfloat16* wattT  = (__hip_bfloat16*)(ws + o_wattT);
  __hip_bfloat16* wdnaT  = (__hip_bfloat16*)(ws + o_wdnaT);
  float* hTf = (float*)(ws + o_hTf);
  float* hTb = (float*)(ws + o_hTb);
  __hip_bfloat16* dvbf  = (__hip_bfloat16*)(ws + o_dvbf);
  __hip_bfloat16* topbf = (__hip_bfloat16*)(ws + o_topbf);
  float* P   = (float*)(ws + o_P);
  float* R   = (float*)(ws + o_R);
  float* dvd = (float*)(ws + o_dvd);
  float* tvd = (float*)(ws + o_tvd);
  float* dsc = (float*)(ws + o_dsc);
  float* tsc = (float*)(ws + o_tsc);
  float* dw  = (float*)(ws + o_dw);
  float* tw  = (float*)(ws + o_tw);
  float* srep32 = (float*)(ws + o_srep32);
  __hip_bfloat16* srepbf = (__hip_bfloat16*)(ws + o_srepbf);
  float* gif = (float*)(ws + o_gif);
  float* gib = (float*)(ws + o_gib);
  float* Q = (float*)(ws + o_Q);
  float* U = (float*)(ws + o_U);

  // 1. sentence means -> padded bf16 activations
  sent_means_kernel<<<M, EP, 0, stream>>>(word_ids, emb, svbf);
  // 2. weight prep (fp32 -> bf16)
  pad_wih_kernel<<<(768 * EP) / 256, 256, 0, stream>>>(wih_f, wpadf);
  pad_wih_kernel<<<(768 * EP) / 256, 256, 0, stream>>>(wih_b, wpadb);
  whh_interleave_kernel<<<(768 * Hd) / 256, 256, 0, stream>>>(whh_f, whhil_f);
  whh_interleave_kernel<<<(768 * Hd) / 256, 256, 0, stream>>>(whh_b, whhil_b);
  transpose_att_kernel<<<(1024 * 1024) / 256, 256, 0, stream>>>(w_att, wattT);
  transpose_dna_kernel<<<(Dd * 1024) / 256, 256, 0, stream>>>(w_dna, wdnaT);
  // 3. input projections gi = sv @ Wih^T + bih
  launch_gemm(svbf, EP, wpadf, EP, gif, 768, M, 768, EP, bih_f, stream);
  launch_gemm(svbf, EP, wpadb, EP, gib, 768, M, 768, EP, bih_b, stream);
  // 4. bidirectional GRU recurrence
  gru_kernel<<<64, 768, 0, stream>>>(gif, gib, whhil_f, whhil_b, bhh_f, bhh_b,
                                     srep32, srepbf, hTf, hTb);
  // 5/6. doc_vec + topic_mat
  docvec_kernel<<<Bd, 512, 0, stream>>>(hTf, hTb, dvbf);
  topic_kernel<<<Bd * Td, 256, 0, stream>>>(tse, srep32, topbf);
  // 7. attention/dense GEMMs
  //   Q = sent_rep @ W_att[512:, :]   (k-offset 512 into wattT rows)
  launch_gemm(srepbf, 512, wattT + 512, 1024, Q, 1024, M, 1024, 512, nullptr, stream);
  //   P = doc_vec @ W_att[:512, :]
  launch_gemm(dvbf, 512, wattT, 1024, P, 1024, Bd, 1024, 512, nullptr, stream);
  //   R = topic_mat @ W_att[:512, :]
  launch_gemm(topbf, 512, wattT, 1024, R, 1024, Bd * Td, 1024, 512, nullptr, stream);
  //   U = sent_rep @ W_dna[:512, :]
  launch_gemm(srepbf, 512, wdnaT, 1024, U, Dd, M, Dd, 512, nullptr, stream);
  //   dvd = doc_vec @ W_dna[512:, :]
  launch_gemm(dvbf, 512, wdnaT + 512, 1024, dvd, Dd, Bd, Dd, 512, nullptr, stream);
  //   tvd = topic_mat @ W_dna[512:, :]
  launch_gemm(topbf, 512, wdnaT + 512, 1024, tvd, Dd, Bd * Td, Dd, 512, nullptr, stream);
  // 8. scores + softmax
  scores_kernel<<<M, 256, 0, stream>>>(P, R, Q, v_att, tse, dsc, tsc);
  softmax_kernel<<<Bd, 256, 0, stream>>>(dsc, tsc, dw, tw);
  // 9. fused dense head -> logits (fp32)
  final_kernel<<<M, 256, 0, stream>>>(U, dvd, tvd, dw, tw, b_dna, w_out, b_out, tse, out);
}

// Round 5
// 679.740 us; speedup vs baseline: 4.2335x; 4.2333x over previous
//
#include <hip/hip_runtime.h>
#include <hip/hip_bf16.h>
#include <math.h>

// Dims (fixed by the problem)
#define Bd 32
#define Sd 256
#define Ld 24
#define Ed 300
#define Hd 256
#define Td 16
#define Dd 256
#define EP 320   // E padded to multiple of 32

using short8 = __attribute__((ext_vector_type(8))) short;
using f32x4  = __attribute__((ext_vector_type(4))) float;

__device__ __forceinline__ float sigm(float x) { return 1.f / (1.f + expf(-x)); }

// ---------------------------------------------------------------------------
// 1. sentence means: A_pad[r][k] = bf16(mean_w emb[word_ids[r][w]][k]), k<300, else 0
// grid 8192, block 320. emb is FLOAT32.
__global__ void sent_means_kernel(const int* __restrict__ wids,
                                  const float* __restrict__ emb,
                                  __hip_bfloat16* __restrict__ apad) {
  int r = blockIdx.x;
  __shared__ int ids[Ld];
  int tid = threadIdx.x;
  if (tid < Ld) ids[tid] = wids[r * Ld + tid];
  __syncthreads();
  float acc = 0.f;
  if (tid < Ed) {
#pragma unroll
    for (int w = 0; w < Ld; ++w) acc += emb[(size_t)ids[w] * Ed + tid];
    acc *= (1.f / 24.f);
  }
  apad[r * EP + tid] = __float2bfloat16(tid < Ed ? acc : 0.f);
}

// ---------------------------------------------------------------------------
// 2. weight prep (all sources FLOAT32 -> bf16 for MFMA)
__global__ void pad_wih_kernel(const float* __restrict__ src,
                               __hip_bfloat16* __restrict__ dst) {
  int i = blockIdx.x * 256 + threadIdx.x;   // 768*320
  if (i >= 768 * EP) return;
  int n = i / EP, k = i % EP;
  dst[i] = __float2bfloat16(k < Ed ? src[n * Ed + k] : 0.f);
}
__global__ void f2bf_kernel(const float* __restrict__ src,
                            __hip_bfloat16* __restrict__ dst, int n) {
  int i = blockIdx.x * 256 + threadIdx.x;
  if (i < n) dst[i] = __float2bfloat16(src[i]);
}
__global__ void transpose_att_kernel(const float* __restrict__ src,
                                     __hip_bfloat16* __restrict__ dst) {
  int i = blockIdx.x * 256 + threadIdx.x;   // 1024*1024: dst[n][k] = src[k][n]
  int n = i >> 10, k = i & 1023;
  dst[i] = __float2bfloat16(src[k * 1024 + n]);
}
__global__ void transpose_dna_kernel(const float* __restrict__ src,
                                     __hip_bfloat16* __restrict__ dst) {
  int i = blockIdx.x * 256 + threadIdx.x;   // 256*1024: dst[n][k] = src[k][n]
  int n = i >> 10, k = i & 1023;
  dst[i] = __float2bfloat16(src[k * Dd + n]);
}

// ---------------------------------------------------------------------------
// 3. MFMA GEMM: C[M,N] = A[M,K] @ W[N,K]^T (+bias[n]); A,W bf16 row-major, C fp32.
// N % 64 == 0, K % 32 == 0; M arbitrary (loads clamped, stores masked).
__global__ __launch_bounds__(256) void gemm_xwt_kernel(
    const __hip_bfloat16* __restrict__ A, int lda,
    const __hip_bfloat16* __restrict__ W, int ldw,
    float* __restrict__ C, int ldc,
    int M, int N, int K,
    const float* __restrict__ bias) {
  __shared__ unsigned short la[64][32];
  __shared__ unsigned short lb[64][32];
  const int tid = threadIdx.x;
  const int m0 = blockIdx.x * 64, n0 = blockIdx.y * 64;
  const int lane = tid & 63, wid = tid >> 6;
  const int wm = (wid >> 1) * 32, wn = (wid & 1) * 32;
  const int lrow = tid >> 2, lcol = (tid & 3) * 8;
  f32x4 acc00 = {0.f, 0.f, 0.f, 0.f}, acc01 = {0.f, 0.f, 0.f, 0.f};
  f32x4 acc10 = {0.f, 0.f, 0.f, 0.f}, acc11 = {0.f, 0.f, 0.f, 0.f};
  int arow = m0 + lrow; if (arow > M - 1) arow = M - 1;
  const int brow = n0 + lrow;
  const int fr = lane & 15, fq = (lane >> 4) * 8;
  for (int k0 = 0; k0 < K; k0 += 32) {
    uint4 av = *(const uint4*)(A + (size_t)arow * lda + k0 + lcol);
    uint4 bv = *(const uint4*)(W + (size_t)brow * ldw + k0 + lcol);
    *(uint4*)(&la[lrow][lcol]) = av;
    *(uint4*)(&lb[lrow][lcol]) = bv;
    __syncthreads();
    short8 a0 = *(const short8*)(&la[wm + fr][fq]);
    short8 a1 = *(const short8*)(&la[wm + 16 + fr][fq]);
    short8 b0 = *(const short8*)(&lb[wn + fr][fq]);
    short8 b1 = *(const short8*)(&lb[wn + 16 + fr][fq]);
    acc00 = __builtin_amdgcn_mfma_f32_16x16x32_bf16(a0, b0, acc00, 0, 0, 0);
    acc01 = __builtin_amdgcn_mfma_f32_16x16x32_bf16(a0, b1, acc01, 0, 0, 0);
    acc10 = __builtin_amdgcn_mfma_f32_16x16x32_bf16(a1, b0, acc10, 0, 0, 0);
    acc11 = __builtin_amdgcn_mfma_f32_16x16x32_bf16(a1, b1, acc11, 0, 0, 0);
    __syncthreads();
  }
  const int rq = (lane >> 4) * 4;
  f32x4 accs[2][2] = {{acc00, acc01}, {acc10, acc11}};
  for (int i = 0; i < 2; ++i)
    for (int j = 0; j < 2; ++j) {
      int n = n0 + wn + j * 16 + fr;
      float bv = bias ? bias[n] : 0.f;
      for (int r2 = 0; r2 < 4; ++r2) {
        int m = m0 + wm + i * 16 + rq + r2;
        if (m < M) C[(size_t)m * ldc + n] = accs[i][j][r2] + bv;
      }
    }
}

// ---------------------------------------------------------------------------
// 4. Persistent-weight MFMA GRU. grid 64 (dir = blk>>5, b = blk&31), block 512.
// Whh (bf16, [768][256]) lives in registers as MFMA B-fragments: wave w owns
// gate rows [w*96, w*96+96) = 6 N-subtiles x 8 K-tiles = 48 short8 = 192 VGPRs.
// h lives in LDS as a 16x256 bf16 A-tile (only row 0 = real batch; rows 1-15
// stay zero). Per step: 8 ds_read_b128/wave + 48 MFMA/wave, then 4 waves do
// the gate nonlinearity in fp32 (h32 kept fp32; only the matmul input is bf16).
__global__ __launch_bounds__(512, 2) void gru_mfma_kernel(
    const float* __restrict__ gi_f, const float* __restrict__ gi_b,
    const __hip_bfloat16* __restrict__ whhbf_f, const __hip_bfloat16* __restrict__ whhbf_b,
    const float* __restrict__ bhh_f, const float* __restrict__ bhh_b,
    float* __restrict__ sent_rep, __hip_bfloat16* __restrict__ sent_rep_bf,
    float* __restrict__ hT_f, float* __restrict__ hT_b) {
  __shared__ __hip_bfloat16 h_bf[16 * 256];  // A-tile: row m=0 real, 1..15 zero
  __shared__ float h32[256];
  __shared__ float gh[768];
  const int blk = blockIdx.x;
  const int dir = blk >> 5, b = blk & 31;
  const int tid = threadIdx.x;
  const int lane = tid & 63, w = tid >> 6;
  const float* gi = dir ? gi_b : gi_f;
  const __hip_bfloat16* whh = dir ? whhbf_b : whhbf_f;
  const float* bhh = dir ? bhh_b : bhh_f;

  for (int i = tid; i < 16 * 256; i += 512) h_bf[i] = __float2bfloat16(0.f);
  if (tid < 256) h32[tid] = 0.f;

  // one-time weight fragment load
  short8 bfrag[6][8];
  {
    const int n0 = w * 96 + (lane & 15);
    const int kq = (lane >> 4) * 8;
#pragma unroll
    for (int nt = 0; nt < 6; ++nt)
#pragma unroll
      for (int kt = 0; kt < 8; ++kt)
        bfrag[nt][kt] = *(const short8*)(whh + (size_t)(n0 + nt * 16) * 256 + kt * 32 + kq);
  }
  float bhr = 0.f, bhz = 0.f, bhn = 0.f;
  if (tid < 256) { bhr = bhh[tid]; bhz = bhh[256 + tid]; bhn = bhh[512 + tid]; }
  __syncthreads();

  const int arow = (lane & 15) * 256;
  const int akq = (lane >> 4) * 8;

  for (int t = 0; t < Sd; ++t) {
    const int s = dir ? (Sd - 1 - t) : t;
    const size_t row = (size_t)((b << 8) + s);
    // issue gi loads early; latency hidden by the MFMA phase (drained at barrier)
    float gir = 0.f, giz = 0.f, gin = 0.f;
    if (tid < 256) {
      gir = gi[row * 768 + tid];
      giz = gi[row * 768 + 256 + tid];
      gin = gi[row * 768 + 512 + tid];
    }
    f32x4 acc[6];
#pragma unroll
    for (int nt = 0; nt < 6; ++nt) acc[nt] = (f32x4){0.f, 0.f, 0.f, 0.f};
    short8 a_cur = *(const short8*)(&h_bf[arow + akq]);
#pragma unroll
    for (int kt = 0; kt < 8; ++kt) {
      short8 a_nxt = a_cur;
      if (kt < 7) a_nxt = *(const short8*)(&h_bf[arow + (kt + 1) * 32 + akq]);
#pragma unroll
      for (int nt = 0; nt < 6; ++nt)
        acc[nt] = __builtin_amdgcn_mfma_f32_16x16x32_bf16(a_cur, bfrag[nt][kt], acc[nt], 0, 0, 0);
      a_cur = a_nxt;
    }
    // C/D layout: col=lane&15 (gate within subtile), row=(lane>>4)*4+reg (batch).
    // batch m=0 sits in lanes 0..15, reg 0.
    if (lane < 16) {
#pragma unroll
      for (int nt = 0; nt < 6; ++nt)
        gh[w * 96 + nt * 16 + lane] = acc[nt][0];
    }
    __syncthreads();
    if (tid < 256) {
      float r = sigm(gir + gh[tid] + bhr);
      float z = sigm(giz + gh[256 + tid] + bhz);
      float n = tanhf(gin + r * (gh[512 + tid] + bhn));
      float hn = (1.f - z) * n + z * h32[tid];
      h32[tid] = hn;
      h_bf[tid] = __float2bfloat16(hn);   // row 0 of the A-tile
      const int col = dir ? (256 + tid) : tid;
      sent_rep[row * 512 + col] = hn;
      sent_rep_bf[row * 512 + col] = __float2bfloat16(hn);
    }
    __syncthreads();
  }
  if (tid < 256) (dir ? hT_b : hT_f)[b * 256 + tid] = h32[tid];
}

// ---------------------------------------------------------------------------
// 5. doc_vec per torch view(B,2H) on stacked [2,B,H]. grid 32, block 512.
__global__ void docvec_kernel(const float* __restrict__ hTf, const float* __restrict__ hTb,
                              __hip_bfloat16* __restrict__ dv) {
  int b = blockIdx.x, jj = threadIdx.x;
  int idx = b * 512 + jj;
  int dsel = idx >> 13;            // /8192
  int rem = idx & 8191;
  int bp = rem >> 8, hp = rem & 255;
  float v = (dsel ? hTb : hTf)[bp * Hd + hp];
  dv[idx] = __float2bfloat16(v);
}

// 6. topic_mat via boundary differencing. grid 512 (b*16+t), block 256.
__global__ void topic_kernel(const int* __restrict__ tse, const float* __restrict__ sent_rep,
                             __hip_bfloat16* __restrict__ topic_bf) {
  int bt = blockIdx.x;
  int b = bt >> 4;
  int st = tse[bt * 2], en = tse[bt * 2 + 1];   // 1-indexed
  int dd = threadIdx.x;
  auto pad = [&](int i, int col) -> float {
    if (i < 1 || i > Sd) return 0.f;
    return sent_rep[((size_t)((b << 8) + (i - 1))) * 512 + col];
  };
  float fwd = pad(en, dd) - pad(st - 1, dd);
  float bwd = pad(st, Hd + dd) - pad(en + 1, Hd + dd);
  topic_bf[(size_t)bt * 512 + dd] = __float2bfloat16(fwd);
  topic_bf[(size_t)bt * 512 + Hd + dd] = __float2bfloat16(bwd);
}

// ---------------------------------------------------------------------------
// 7. attention scores. grid 8192 (b*256+s), block 256.
__global__ void scores_kernel(const float* __restrict__ P, const float* __restrict__ R,
                              const float* __restrict__ Q, const float* __restrict__ v_att,
                              const int* __restrict__ tse,
                              float* __restrict__ dsc, float* __restrict__ tsc) {
  int r = blockIdx.x;
  int b = r >> 8, s = r & 255;
  int tid = threadIdx.x;
  int tsel = Td - 1;
  for (int t = 0; t < Td; ++t) {
    if (tse[(b * Td + t) * 2 + 1] >= s + 1) { tsel = t; break; }
  }
  const float* q = Q + (size_t)r * 1024;
  const float* p = P + (size_t)b * 1024;
  const float* rr = R + (size_t)(b * Td + tsel) * 1024;
  float accd = 0.f, acct = 0.f;
  for (int n = tid; n < 1024; n += 256) {
    float qv = q[n];
    float vv = v_att[n];
    accd += tanhf(p[n] + qv) * vv;
    acct += tanhf(rr[n] + qv) * vv;
  }
  __shared__ float s1[256], s2[256];
  s1[tid] = accd; s2[tid] = acct;
  __syncthreads();
  for (int off = 128; off > 0; off >>= 1) {
    if (tid < off) { s1[tid] += s1[tid + off]; s2[tid] += s2[tid + off]; }
    __syncthreads();
  }
  if (tid == 0) { dsc[r] = s1[0]; tsc[r] = s2[0]; }
}

// 8. softmax over s per batch (both score sets). grid 32, block 256.
__global__ void softmax_kernel(const float* __restrict__ dsc, const float* __restrict__ tsc,
                               float* __restrict__ dw, float* __restrict__ tw) {
  int b = blockIdx.x, s = threadIdx.x;
  __shared__ float red[256];
  for (int which = 0; which < 2; ++which) {
    const float* src = which ? tsc : dsc;
    float v = src[b * Sd + s];
    red[s] = v; __syncthreads();
    for (int off = 128; off > 0; off >>= 1) {
      if (s < off) red[s] = fmaxf(red[s], red[s + off]);
      __syncthreads();
    }
    float m = red[0]; __syncthreads();
    float e = expf(v - m);
    red[s] = e; __syncthreads();
    for (int off = 128; off > 0; off >>= 1) {
      if (s < off) red[s] += red[s + off];
      __syncthreads();
    }
    float sum = red[0]; __syncthreads();
    (which ? tw : dw)[b * Sd + s] = e / sum;
  }
}

// 9. final head. grid 8192, block 256. OUTPUT IS FP32.
__global__ void final_kernel(const float* __restrict__ U, const float* __restrict__ dvd,
                             const float* __restrict__ tvd, const float* __restrict__ dw,
                             const float* __restrict__ tw, const float* __restrict__ b_dna,
                             const float* __restrict__ w_out,
                             const float* __restrict__ b_out,
                             const int* __restrict__ tse, float* __restrict__ out) {
  int r = blockIdx.x;
  int b = r >> 8, s = r & 255;
  int dd = threadIdx.x;
  int tsel = Td - 1;
  for (int t = 0; t < Td; ++t) {
    if (tse[(b * Td + t) * 2 + 1] >= s + 1) { tsel = t; break; }
  }
  float wdv = dw[b * Sd + s], wtv = tw[b * Sd + s];
  float x = U[(size_t)r * Dd + dd] + wdv * dvd[b * Dd + dd] +
            wtv * tvd[(size_t)(b * Td + tsel) * Dd + dd] + b_dna[dd];
  x = fmaxf(x, 0.f);
  float term = x * w_out[dd];
  __shared__ float red[256];
  red[dd] = term; __syncthreads();
  for (int off = 128; off > 0; off >>= 1) {
    if (dd < off) red[dd] += red[dd + off];
    __syncthreads();
  }
  if (dd == 0) out[r] = red[0] + b_out[0];
}

// ---------------------------------------------------------------------------
static void launch_gemm(const __hip_bfloat16* A, int lda, const __hip_bfloat16* W, int ldw,
                        float* C, int ldc, int M, int N, int K,
                        const float* bias, hipStream_t stream) {
  dim3 grid((M + 63) / 64, N / 64);
  gemm_xwt_kernel<<<grid, 256, 0, stream>>>(A, lda, W, ldw, C, ldc, M, N, K, bias);
}

extern "C" void kernel_launch(void* const* d_in, const int* in_sizes, int n_in,
                              void* d_out, int out_size, void* d_ws, size_t ws_size,
                              hipStream_t stream) {
  const int* word_ids = (const int*)d_in[0];
  const int* tse      = (const int*)d_in[1];
  const float* emb   = (const float*)d_in[2];
  const float* wih_f = (const float*)d_in[3];
  const float* whh_f = (const float*)d_in[4];
  const float* bih_f = (const float*)d_in[5];
  const float* bhh_f = (const float*)d_in[6];
  const float* wih_b = (const float*)d_in[7];
  const float* whh_b = (const float*)d_in[8];
  const float* bih_b = (const float*)d_in[9];
  const float* bhh_b = (const float*)d_in[10];
  const float* w_att = (const float*)d_in[11];
  const float* v_att = (const float*)d_in[12];
  const float* w_dna = (const float*)d_in[13];
  const float* b_dna = (const float*)d_in[14];
  const float* w_out = (const float*)d_in[15];
  const float* b_out = (const float*)d_in[16];
  float* out = (float*)d_out;
  char* ws = (char*)d_ws;

  const int M = Bd * Sd;  // 8192

  // workspace layout (bytes)
  size_t off = 0;
  auto alloc = [&](size_t sz) { size_t o = off; off += (sz + 255) & ~(size_t)255; return o; };
  size_t o_svbf   = alloc((size_t)M * EP * 2);          // A_pad bf16 [8192,320]
  size_t o_wpadf  = alloc((size_t)768 * EP * 2);
  size_t o_wpadb  = alloc((size_t)768 * EP * 2);
  size_t o_whhbf  = alloc((size_t)768 * Hd * 2 * 2);    // whh f+b bf16
  size_t o_wattT  = alloc((size_t)1024 * 1024 * 2);     // WattT[n][k] bf16
  size_t o_wdnaT  = alloc((size_t)Dd * 1024 * 2);       // WdnaT[n][k] bf16
  size_t o_hTf    = alloc((size_t)Bd * Hd * 4);
  size_t o_hTb    = alloc((size_t)Bd * Hd * 4);
  size_t o_dvbf   = alloc((size_t)Bd * 512 * 2);        // doc_vec bf16
  size_t o_topbf  = alloc((size_t)Bd * Td * 512 * 2);   // topic_mat bf16
  size_t o_P      = alloc((size_t)Bd * 1024 * 4);
  size_t o_R      = alloc((size_t)Bd * Td * 1024 * 4);
  size_t o_dvd    = alloc((size_t)Bd * Dd * 4);
  size_t o_tvd    = alloc((size_t)Bd * Td * Dd * 4);
  size_t o_dsc    = alloc((size_t)Bd * Sd * 4);
  size_t o_tsc    = alloc((size_t)Bd * Sd * 4);
  size_t o_dw     = alloc((size_t)Bd * Sd * 4);
  size_t o_tw     = alloc((size_t)Bd * Sd * 4);
  size_t o_srep32 = alloc((size_t)M * 512 * 4);         // sent_rep fp32
  size_t o_srepbf = alloc((size_t)M * 512 * 2);         // sent_rep bf16
  size_t o_gif    = alloc((size_t)M * 768 * 4);         // gi fwd fp32
  size_t o_gib    = alloc((size_t)M * 768 * 4);         // gi bwd fp32
  // Q [8192,1024] f32 and U [8192,256] f32 overlay the dead gi region after GRU
  size_t o_Q = o_gif;
  size_t o_U = o_gif + (size_t)M * 1024 * 4;
  (void)ws_size;

  __hip_bfloat16* svbf   = (__hip_bfloat16*)(ws + o_svbf);
  __hip_bfloat16* wpadf  = (__hip_bfloat16*)(ws + o_wpadf);
  __hip_bfloat16* wpadb  = (__hip_bfloat16*)(ws + o_wpadb);
  __hip_bfloat16* whhbf_f = (__hip_bfloat16*)(ws + o_whhbf);
  __hip_bfloat16* whhbf_b = whhbf_f + 768 * Hd;
  __hip_bfloat16* wattT  = (__hip_bfloat16*)(ws + o_wattT);
  __hip_bfloat16* wdnaT  = (__hip_bfloat16*)(ws + o_wdnaT);
  float* hTf = (float*)(ws + o_hTf);
  float* hTb = (float*)(ws + o_hTb);
  __hip_bfloat16* dvbf  = (__hip_bfloat16*)(ws + o_dvbf);
  __hip_bfloat16* topbf = (__hip_bfloat16*)(ws + o_topbf);
  float* P   = (float*)(ws + o_P);
  float* R   = (float*)(ws + o_R);
  float* dvd = (float*)(ws + o_dvd);
  float* tvd = (float*)(ws + o_tvd);
  float* dsc = (float*)(ws + o_dsc);
  float* tsc = (float*)(ws + o_tsc);
  float* dw  = (float*)(ws + o_dw);
  float* tw  = (float*)(ws + o_tw);
  float* srep32 = (float*)(ws + o_srep32);
  __hip_bfloat16* srepbf = (__hip_bfloat16*)(ws + o_srepbf);
  float* gif = (float*)(ws + o_gif);
  float* gib = (float*)(ws + o_gib);
  float* Q = (float*)(ws + o_Q);
  float* U = (float*)(ws + o_U);

  // 1. sentence means -> padded bf16 activations
  sent_means_kernel<<<M, EP, 0, stream>>>(word_ids, emb, svbf);
  // 2. weight prep (fp32 -> bf16)
  pad_wih_kernel<<<(768 * EP) / 256, 256, 0, stream>>>(wih_f, wpadf);
  pad_wih_kernel<<<(768 * EP) / 256, 256, 0, stream>>>(wih_b, wpadb);
  f2bf_kernel<<<(768 * Hd) / 256, 256, 0, stream>>>(whh_f, whhbf_f, 768 * Hd);
  f2bf_kernel<<<(768 * Hd) / 256, 256, 0, stream>>>(whh_b, whhbf_b, 768 * Hd);
  transpose_att_kernel<<<(1024 * 1024) / 256, 256, 0, stream>>>(w_att, wattT);
  transpose_dna_kernel<<<(Dd * 1024) / 256, 256, 0, stream>>>(w_dna, wdnaT);
  // 3. input projections gi = sv @ Wih^T + bih
  launch_gemm(svbf, EP, wpadf, EP, gif, 768, M, 768, EP, bih_f, stream);
  launch_gemm(svbf, EP, wpadb, EP, gib, 768, M, 768, EP, bih_b, stream);
  // 4. bidirectional GRU recurrence (persistent-weight MFMA)
  gru_mfma_kernel<<<64, 512, 0, stream>>>(gif, gib, whhbf_f, whhbf_b, bhh_f, bhh_b,
                                          srep32, srepbf, hTf, hTb);
  // 5/6. doc_vec + topic_mat
  docvec_kernel<<<Bd, 512, 0, stream>>>(hTf, hTb, dvbf);
  topic_kernel<<<Bd * Td, 256, 0, stream>>>(tse, srep32, topbf);
  // 7. attention/dense GEMMs
  launch_gemm(srepbf, 512, wattT + 512, 1024, Q, 1024, M, 1024, 512, nullptr, stream);
  launch_gemm(dvbf, 512, wattT, 1024, P, 1024, Bd, 1024, 512, nullptr, stream);
  launch_gemm(topbf, 512, wattT, 1024, R, 1024, Bd * Td, 1024, 512, nullptr, stream);
  launch_gemm(srepbf, 512, wdnaT, 1024, U, Dd, M, Dd, 512, nullptr, stream);
  launch_gemm(dvbf, 512, wdnaT + 512, 1024, dvd, Dd, Bd, Dd, 512, nullptr, stream);
  launch_gemm(topbf, 512, wdnaT + 512, 1024, tvd, Dd, Bd * Td, Dd, 512, nullptr, stream);
  // 8. scores + softmax
  scores_kernel<<<M, 256, 0, stream>>>(P, R, Q, v_att, tse, dsc, tsc);
  softmax_kernel<<<Bd, 256, 0, stream>>>(dsc, tsc, dw, tw);
  // 9. fused dense head -> logits (fp32)
  final_kernel<<<M, 256, 0, stream>>>(U, dvd, tvd, dw, tw, b_dna, w_out, b_out, tse, out);
}

// Round 6
// 616.095 us; speedup vs baseline: 4.6709x; 1.1033x over previous
//
#include <hip/hip_runtime.h>
#include <hip/hip_bf16.h>
#include <math.h>

// Dims (fixed by the problem)
#define Bd 32
#define Sd 256
#define Ld 24
#define Ed 300
#define Hd 256
#define Td 16
#define Dd 256
#define EP 320    // E padded to multiple of 32
#define HPAD 264  // 256 + 8: pad A-tile row stride (528 B) to break 16-way LDS bank conflicts

using short8 = __attribute__((ext_vector_type(8))) short;
using f32x4  = __attribute__((ext_vector_type(4))) float;

// fast transcendentals (v_exp_f32 path; saturate correctly at +-inf)
__device__ __forceinline__ float fsigm(float x) { return 1.f / (1.f + __expf(-x)); }
__device__ __forceinline__ float ftanh(float x) {
  float e = __expf(2.f * x);
  return 1.f - 2.f / (e + 1.f);
}

// ---------------------------------------------------------------------------
// 1. sentence means: A_pad[r][k] = bf16(mean_w emb[word_ids[r][w]][k]), k<300, else 0
// grid 8192, block 320. emb is FLOAT32.
__global__ void sent_means_kernel(const int* __restrict__ wids,
                                  const float* __restrict__ emb,
                                  __hip_bfloat16* __restrict__ apad) {
  int r = blockIdx.x;
  __shared__ int ids[Ld];
  int tid = threadIdx.x;
  if (tid < Ld) ids[tid] = wids[r * Ld + tid];
  __syncthreads();
  float acc = 0.f;
  if (tid < Ed) {
#pragma unroll
    for (int w = 0; w < Ld; ++w) acc += emb[(size_t)ids[w] * Ed + tid];
    acc *= (1.f / 24.f);
  }
  apad[r * EP + tid] = __float2bfloat16(tid < Ed ? acc : 0.f);
}

// ---------------------------------------------------------------------------
// 2. weight prep (all sources FLOAT32 -> bf16 for MFMA)
__global__ void pad_wih_kernel(const float* __restrict__ src,
                               __hip_bfloat16* __restrict__ dst) {
  int i = blockIdx.x * 256 + threadIdx.x;   // 768*320
  if (i >= 768 * EP) return;
  int n = i / EP, k = i % EP;
  dst[i] = __float2bfloat16(k < Ed ? src[n * Ed + k] : 0.f);
}
__global__ void f2bf_kernel(const float* __restrict__ src,
                            __hip_bfloat16* __restrict__ dst, int n) {
  int i = blockIdx.x * 256 + threadIdx.x;
  if (i < n) dst[i] = __float2bfloat16(src[i]);
}
__global__ void transpose_att_kernel(const float* __restrict__ src,
                                     __hip_bfloat16* __restrict__ dst) {
  int i = blockIdx.x * 256 + threadIdx.x;   // 1024*1024: dst[n][k] = src[k][n]
  int n = i >> 10, k = i & 1023;
  dst[i] = __float2bfloat16(src[k * 1024 + n]);
}
__global__ void transpose_dna_kernel(const float* __restrict__ src,
                                     __hip_bfloat16* __restrict__ dst) {
  int i = blockIdx.x * 256 + threadIdx.x;   // 256*1024: dst[n][k] = src[k][n]
  int n = i >> 10, k = i & 1023;
  dst[i] = __float2bfloat16(src[k * Dd + n]);
}

// ---------------------------------------------------------------------------
// 3. MFMA GEMM: C[M,N] = A[M,K] @ W[N,K]^T (+bias[n]); A,W bf16 row-major, C fp32.
// N % 64 == 0, K % 32 == 0; M arbitrary (loads clamped, stores masked).
__global__ __launch_bounds__(256) void gemm_xwt_kernel(
    const __hip_bfloat16* __restrict__ A, int lda,
    const __hip_bfloat16* __restrict__ W, int ldw,
    float* __restrict__ C, int ldc,
    int M, int N, int K,
    const float* __restrict__ bias) {
  __shared__ unsigned short la[64][32];
  __shared__ unsigned short lb[64][32];
  const int tid = threadIdx.x;
  const int m0 = blockIdx.x * 64, n0 = blockIdx.y * 64;
  const int lane = tid & 63, wid = tid >> 6;
  const int wm = (wid >> 1) * 32, wn = (wid & 1) * 32;
  const int lrow = tid >> 2, lcol = (tid & 3) * 8;
  f32x4 acc00 = {0.f, 0.f, 0.f, 0.f}, acc01 = {0.f, 0.f, 0.f, 0.f};
  f32x4 acc10 = {0.f, 0.f, 0.f, 0.f}, acc11 = {0.f, 0.f, 0.f, 0.f};
  int arow = m0 + lrow; if (arow > M - 1) arow = M - 1;
  const int brow = n0 + lrow;
  const int fr = lane & 15, fq = (lane >> 4) * 8;
  for (int k0 = 0; k0 < K; k0 += 32) {
    uint4 av = *(const uint4*)(A + (size_t)arow * lda + k0 + lcol);
    uint4 bv = *(const uint4*)(W + (size_t)brow * ldw + k0 + lcol);
    *(uint4*)(&la[lrow][lcol]) = av;
    *(uint4*)(&lb[lrow][lcol]) = bv;
    __syncthreads();
    short8 a0 = *(const short8*)(&la[wm + fr][fq]);
    short8 a1 = *(const short8*)(&la[wm + 16 + fr][fq]);
    short8 b0 = *(const short8*)(&lb[wn + fr][fq]);
    short8 b1 = *(const short8*)(&lb[wn + 16 + fr][fq]);
    acc00 = __builtin_amdgcn_mfma_f32_16x16x32_bf16(a0, b0, acc00, 0, 0, 0);
    acc01 = __builtin_amdgcn_mfma_f32_16x16x32_bf16(a0, b1, acc01, 0, 0, 0);
    acc10 = __builtin_amdgcn_mfma_f32_16x16x32_bf16(a1, b0, acc10, 0, 0, 0);
    acc11 = __builtin_amdgcn_mfma_f32_16x16x32_bf16(a1, b1, acc11, 0, 0, 0);
    __syncthreads();
  }
  const int rq = (lane >> 4) * 4;
  f32x4 accs[2][2] = {{acc00, acc01}, {acc10, acc11}};
  for (int i = 0; i < 2; ++i)
    for (int j = 0; j < 2; ++j) {
      int n = n0 + wn + j * 16 + fr;
      float bv = bias ? bias[n] : 0.f;
      for (int r2 = 0; r2 < 4; ++r2) {
        int m = m0 + wm + i * 16 + rq + r2;
        if (m < M) C[(size_t)m * ldc + n] = accs[i][j][r2] + bv;
      }
    }
}

// ---------------------------------------------------------------------------
// 4. Persistent-weight MFMA GRU. grid 64 (dir = blk>>5, b = blk&31), block 512.
// Whh register-resident as B-fragments (48 short8/wave). h in a padded 16xHPAD
// bf16 LDS A-tile (row 0 real). sent_rep writes staged in LDS, flushed every
// 8 steps to amortize the vmcnt(0) store drain at the per-step barrier.
__global__ __launch_bounds__(512, 2) void gru_mfma_kernel(
    const float* __restrict__ gi_f, const float* __restrict__ gi_b,
    const __hip_bfloat16* __restrict__ whhbf_f, const __hip_bfloat16* __restrict__ whhbf_b,
    const float* __restrict__ bhh_f, const float* __restrict__ bhh_b,
    float* __restrict__ sent_rep, __hip_bfloat16* __restrict__ sent_rep_bf,
    float* __restrict__ hT_f, float* __restrict__ hT_b) {
  __shared__ __hip_bfloat16 h_bf[16 * HPAD];  // A-tile: row m=0 real, 1..15 zero
  __shared__ float h32[256];
  __shared__ float gh[768];
  __shared__ float stg32[8][256];             // sent_rep staging (8 steps)
  __shared__ __hip_bfloat16 stgbf[8][256];
  const int blk = blockIdx.x;
  const int dir = blk >> 5, b = blk & 31;
  const int tid = threadIdx.x;
  const int lane = tid & 63, w = tid >> 6;
  const float* gi = dir ? gi_b : gi_f;
  const __hip_bfloat16* whh = dir ? whhbf_b : whhbf_f;
  const float* bhh = dir ? bhh_b : bhh_f;

  for (int i = tid; i < 16 * HPAD; i += 512) h_bf[i] = __float2bfloat16(0.f);
  if (tid < 256) h32[tid] = 0.f;

  // one-time weight fragment load
  short8 bfrag[6][8];
  {
    const int n0 = w * 96 + (lane & 15);
    const int kq = (lane >> 4) * 8;
#pragma unroll
    for (int nt = 0; nt < 6; ++nt)
#pragma unroll
      for (int kt = 0; kt < 8; ++kt)
        bfrag[nt][kt] = *(const short8*)(whh + (size_t)(n0 + nt * 16) * 256 + kt * 32 + kq);
  }
  float bhr = 0.f, bhz = 0.f, bhn = 0.f;
  if (tid < 256) { bhr = bhh[tid]; bhz = bhh[256 + tid]; bhn = bhh[512 + tid]; }
  __syncthreads();

  const int arow = (lane & 15) * HPAD;
  const int akq = (lane >> 4) * 8;

  for (int t = 0; t < Sd; ++t) {
    const int s = dir ? (Sd - 1 - t) : t;
    const size_t row = (size_t)((b << 8) + s);
    // issue gi loads early; latency hidden by the MFMA phase
    float gir = 0.f, giz = 0.f, gin = 0.f;
    if (tid < 256) {
      gir = gi[row * 768 + tid];
      giz = gi[row * 768 + 256 + tid];
      gin = gi[row * 768 + 512 + tid];
    }
    f32x4 acc[6];
#pragma unroll
    for (int nt = 0; nt < 6; ++nt) acc[nt] = (f32x4){0.f, 0.f, 0.f, 0.f};
    short8 a_cur = *(const short8*)(&h_bf[arow + akq]);
#pragma unroll
    for (int kt = 0; kt < 8; ++kt) {
      short8 a_nxt = a_cur;
      if (kt < 7) a_nxt = *(const short8*)(&h_bf[arow + (kt + 1) * 32 + akq]);
#pragma unroll
      for (int nt = 0; nt < 6; ++nt)
        acc[nt] = __builtin_amdgcn_mfma_f32_16x16x32_bf16(a_cur, bfrag[nt][kt], acc[nt], 0, 0, 0);
      a_cur = a_nxt;
    }
    // C/D layout: col=lane&15 (gate row within subtile), row=(lane>>4)*4+reg
    // (batch). batch m=0 sits in lanes 0..15, reg 0.
    if (lane < 16) {
#pragma unroll
      for (int nt = 0; nt < 6; ++nt)
        gh[w * 96 + nt * 16 + lane] = acc[nt][0];
    }
    __syncthreads();
    if (tid < 256) {
      float r = fsigm(gir + gh[tid] + bhr);
      float z = fsigm(giz + gh[256 + tid] + bhz);
      float n = ftanh(gin + r * (gh[512 + tid] + bhn));
      float hn = (1.f - z) * n + z * h32[tid];
      h32[tid] = hn;
      h_bf[tid] = __float2bfloat16(hn);   // row 0 of the A-tile
      stg32[t & 7][tid] = hn;
      stgbf[t & 7][tid] = __float2bfloat16(hn);
    }
    __syncthreads();
    if ((t & 7) == 7) {
      // flush 8 staged steps (2048 elems, 4/thread). Reads complete before the
      // next step's barrier; stage rows are only rewritten after that barrier.
      const int base = t - 7;
#pragma unroll
      for (int i = 0; i < 4; ++i) {
        int idx = tid + i * 512;
        int u = idx >> 8, d = idx & 255;
        int sg = dir ? (255 - (base + u)) : (base + u);
        size_t rowg = (size_t)((b << 8) + sg);
        int col = dir ? (256 + d) : d;
        sent_rep[rowg * 512 + col] = stg32[u][d];
        sent_rep_bf[rowg * 512 + col] = stgbf[u][d];
      }
    }
  }
  if (tid < 256) (dir ? hT_b : hT_f)[b * 256 + tid] = h32[tid];
}

// ---------------------------------------------------------------------------
// 5. doc_vec per torch view(B,2H) on stacked [2,B,H]. grid 32, block 512.
__global__ void docvec_kernel(const float* __restrict__ hTf, const float* __restrict__ hTb,
                              __hip_bfloat16* __restrict__ dv) {
  int b = blockIdx.x, jj = threadIdx.x;
  int idx = b * 512 + jj;
  int dsel = idx >> 13;            // /8192
  int rem = idx & 8191;
  int bp = rem >> 8, hp = rem & 255;
  float v = (dsel ? hTb : hTf)[bp * Hd + hp];
  dv[idx] = __float2bfloat16(v);
}

// 6. topic_mat via boundary differencing. grid 512 (b*16+t), block 256.
__global__ void topic_kernel(const int* __restrict__ tse, const float* __restrict__ sent_rep,
                             __hip_bfloat16* __restrict__ topic_bf) {
  int bt = blockIdx.x;
  int b = bt >> 4;
  int st = tse[bt * 2], en = tse[bt * 2 + 1];   // 1-indexed
  int dd = threadIdx.x;
  auto pad = [&](int i, int col) -> float {
    if (i < 1 || i > Sd) return 0.f;
    return sent_rep[((size_t)((b << 8) + (i - 1))) * 512 + col];
  };
  float fwd = pad(en, dd) - pad(st - 1, dd);
  float bwd = pad(st, Hd + dd) - pad(en + 1, Hd + dd);
  topic_bf[(size_t)bt * 512 + dd] = __float2bfloat16(fwd);
  topic_bf[(size_t)bt * 512 + Hd + dd] = __float2bfloat16(bwd);
}

// ---------------------------------------------------------------------------
// 7. attention scores. grid 8192 (b*256+s), block 256.
__global__ void scores_kernel(const float* __restrict__ P, const float* __restrict__ R,
                              const float* __restrict__ Q, const float* __restrict__ v_att,
                              const int* __restrict__ tse,
                              float* __restrict__ dsc, float* __restrict__ tsc) {
  int r = blockIdx.x;
  int b = r >> 8, s = r & 255;
  int tid = threadIdx.x;
  int tsel = Td - 1;
  for (int t = 0; t < Td; ++t) {
    if (tse[(b * Td + t) * 2 + 1] >= s + 1) { tsel = t; break; }
  }
  const float* q = Q + (size_t)r * 1024;
  const float* p = P + (size_t)b * 1024;
  const float* rr = R + (size_t)(b * Td + tsel) * 1024;
  float accd = 0.f, acct = 0.f;
  for (int n = tid; n < 1024; n += 256) {
    float qv = q[n];
    float vv = v_att[n];
    accd += ftanh(p[n] + qv) * vv;
    acct += ftanh(rr[n] + qv) * vv;
  }
  __shared__ float s1[256], s2[256];
  s1[tid] = accd; s2[tid] = acct;
  __syncthreads();
  for (int off = 128; off > 0; off >>= 1) {
    if (tid < off) { s1[tid] += s1[tid + off]; s2[tid] += s2[tid + off]; }
    __syncthreads();
  }
  if (tid == 0) { dsc[r] = s1[0]; tsc[r] = s2[0]; }
}

// 8. softmax over s per batch (both score sets). grid 32, block 256.
__global__ void softmax_kernel(const float* __restrict__ dsc, const float* __restrict__ tsc,
                               float* __restrict__ dw, float* __restrict__ tw) {
  int b = blockIdx.x, s = threadIdx.x;
  __shared__ float red[256];
  for (int which = 0; which < 2; ++which) {
    const float* src = which ? tsc : dsc;
    float v = src[b * Sd + s];
    red[s] = v; __syncthreads();
    for (int off = 128; off > 0; off >>= 1) {
      if (s < off) red[s] = fmaxf(red[s], red[s + off]);
      __syncthreads();
    }
    float m = red[0]; __syncthreads();
    float e = __expf(v - m);
    red[s] = e; __syncthreads();
    for (int off = 128; off > 0; off >>= 1) {
      if (s < off) red[s] += red[s + off];
      __syncthreads();
    }
    float sum = red[0]; __syncthreads();
    (which ? tw : dw)[b * Sd + s] = e / sum;
  }
}

// 9. final head. grid 8192, block 256. OUTPUT IS FP32.
__global__ void final_kernel(const float* __restrict__ U, const float* __restrict__ dvd,
                             const float* __restrict__ tvd, const float* __restrict__ dw,
                             const float* __restrict__ tw, const float* __restrict__ b_dna,
                             const float* __restrict__ w_out,
                             const float* __restrict__ b_out,
                             const int* __restrict__ tse, float* __restrict__ out) {
  int r = blockIdx.x;
  int b = r >> 8, s = r & 255;
  int dd = threadIdx.x;
  int tsel = Td - 1;
  for (int t = 0; t < Td; ++t) {
    if (tse[(b * Td + t) * 2 + 1] >= s + 1) { tsel = t; break; }
  }
  float wdv = dw[b * Sd + s], wtv = tw[b * Sd + s];
  float x = U[(size_t)r * Dd + dd] + wdv * dvd[b * Dd + dd] +
            wtv * tvd[(size_t)(b * Td + tsel) * Dd + dd] + b_dna[dd];
  x = fmaxf(x, 0.f);
  float term = x * w_out[dd];
  __shared__ float red[256];
  red[dd] = term; __syncthreads();
  for (int off = 128; off > 0; off >>= 1) {
    if (dd < off) red[dd] += red[dd + off];
    __syncthreads();
  }
  if (dd == 0) out[r] = red[0] + b_out[0];
}

// ---------------------------------------------------------------------------
static void launch_gemm(const __hip_bfloat16* A, int lda, const __hip_bfloat16* W, int ldw,
                        float* C, int ldc, int M, int N, int K,
                        const float* bias, hipStream_t stream) {
  dim3 grid((M + 63) / 64, N / 64);
  gemm_xwt_kernel<<<grid, 256, 0, stream>>>(A, lda, W, ldw, C, ldc, M, N, K, bias);
}

extern "C" void kernel_launch(void* const* d_in, const int* in_sizes, int n_in,
                              void* d_out, int out_size, void* d_ws, size_t ws_size,
                              hipStream_t stream) {
  const int* word_ids = (const int*)d_in[0];
  const int* tse      = (const int*)d_in[1];
  const float* emb   = (const float*)d_in[2];
  const float* wih_f = (const float*)d_in[3];
  const float* whh_f = (const float*)d_in[4];
  const float* bih_f = (const float*)d_in[5];
  const float* bhh_f = (const float*)d_in[6];
  const float* wih_b = (const float*)d_in[7];
  const float* whh_b = (const float*)d_in[8];
  const float* bih_b = (const float*)d_in[9];
  const float* bhh_b = (const float*)d_in[10];
  const float* w_att = (const float*)d_in[11];
  const float* v_att = (const float*)d_in[12];
  const float* w_dna = (const float*)d_in[13];
  const float* b_dna = (const float*)d_in[14];
  const float* w_out = (const float*)d_in[15];
  const float* b_out = (const float*)d_in[16];
  float* out = (float*)d_out;
  char* ws = (char*)d_ws;

  const int M = Bd * Sd;  // 8192

  // workspace layout (bytes)
  size_t off = 0;
  auto alloc = [&](size_t sz) { size_t o = off; off += (sz + 255) & ~(size_t)255; return o; };
  size_t o_svbf   = alloc((size_t)M * EP * 2);          // A_pad bf16 [8192,320]
  size_t o_wpadf  = alloc((size_t)768 * EP * 2);
  size_t o_wpadb  = alloc((size_t)768 * EP * 2);
  size_t o_whhbf  = alloc((size_t)768 * Hd * 2 * 2);    // whh f+b bf16
  size_t o_wattT  = alloc((size_t)1024 * 1024 * 2);     // WattT[n][k] bf16
  size_t o_wdnaT  = alloc((size_t)Dd * 1024 * 2);       // WdnaT[n][k] bf16
  size_t o_hTf    = alloc((size_t)Bd * Hd * 4);
  size_t o_hTb    = alloc((size_t)Bd * Hd * 4);
  size_t o_dvbf   = alloc((size_t)Bd * 512 * 2);        // doc_vec bf16
  size_t o_topbf  = alloc((size_t)Bd * Td * 512 * 2);   // topic_mat bf16
  size_t o_P      = alloc((size_t)Bd * 1024 * 4);
  size_t o_R      = alloc((size_t)Bd * Td * 1024 * 4);
  size_t o_dvd    = alloc((size_t)Bd * Dd * 4);
  size_t o_tvd    = alloc((size_t)Bd * Td * Dd * 4);
  size_t o_dsc    = alloc((size_t)Bd * Sd * 4);
  size_t o_tsc    = alloc((size_t)Bd * Sd * 4);
  size_t o_dw     = alloc((size_t)Bd * Sd * 4);
  size_t o_tw     = alloc((size_t)Bd * Sd * 4);
  size_t o_srep32 = alloc((size_t)M * 512 * 4);         // sent_rep fp32
  size_t o_srepbf = alloc((size_t)M * 512 * 2);         // sent_rep bf16
  size_t o_gif    = alloc((size_t)M * 768 * 4);         // gi fwd fp32
  size_t o_gib    = alloc((size_t)M * 768 * 4);         // gi bwd fp32
  // Q [8192,1024] f32 and U [8192,256] f32 overlay the dead gi region after GRU
  size_t o_Q = o_gif;
  size_t o_U = o_gif + (size_t)M * 1024 * 4;
  (void)ws_size;

  __hip_bfloat16* svbf   = (__hip_bfloat16*)(ws + o_svbf);
  __hip_bfloat16* wpadf  = (__hip_bfloat16*)(ws + o_wpadf);
  __hip_bfloat16* wpadb  = (__hip_bfloat16*)(ws + o_wpadb);
  __hip_bfloat16* whhbf_f = (__hip_bfloat16*)(ws + o_whhbf);
  __hip_bfloat16* whhbf_b = whhbf_f + 768 * Hd;
  __hip_bfloat16* wattT  = (__hip_bfloat16*)(ws + o_wattT);
  __hip_bfloat16* wdnaT  = (__hip_bfloat16*)(ws + o_wdnaT);
  float* hTf = (float*)(ws + o_hTf);
  float* hTb = (float*)(ws + o_hTb);
  __hip_bfloat16* dvbf  = (__hip_bfloat16*)(ws + o_dvbf);
  __hip_bfloat16* topbf = (__hip_bfloat16*)(ws + o_topbf);
  float* P   = (float*)(ws + o_P);
  float* R   = (float*)(ws + o_R);
  float* dvd = (float*)(ws + o_dvd);
  float* tvd = (float*)(ws + o_tvd);
  float* dsc = (float*)(ws + o_dsc);
  float* tsc = (float*)(ws + o_tsc);
  float* dw  = (float*)(ws + o_dw);
  float* tw  = (float*)(ws + o_tw);
  float* srep32 = (float*)(ws + o_srep32);
  __hip_bfloat16* srepbf = (__hip_bfloat16*)(ws + o_srepbf);
  float* gif = (float*)(ws + o_gif);
  float* gib = (float*)(ws + o_gib);
  float* Q = (float*)(ws + o_Q);
  float* U = (float*)(ws + o_U);

  // 1. sentence means -> padded bf16 activations
  sent_means_kernel<<<M, EP, 0, stream>>>(word_ids, emb, svbf);
  // 2. weight prep (fp32 -> bf16)
  pad_wih_kernel<<<(768 * EP) / 256, 256, 0, stream>>>(wih_f, wpadf);
  pad_wih_kernel<<<(768 * EP) / 256, 256, 0, stream>>>(wih_b, wpadb);
  f2bf_kernel<<<(768 * Hd) / 256, 256, 0, stream>>>(whh_f, whhbf_f, 768 * Hd);
  f2bf_kernel<<<(768 * Hd) / 256, 256, 0, stream>>>(whh_b, whhbf_b, 768 * Hd);
  transpose_att_kernel<<<(1024 * 1024) / 256, 256, 0, stream>>>(w_att, wattT);
  transpose_dna_kernel<<<(Dd * 1024) / 256, 256, 0, stream>>>(w_dna, wdnaT);
  // 3. input projections gi = sv @ Wih^T + bih
  launch_gemm(svbf, EP, wpadf, EP, gif, 768, M, 768, EP, bih_f, stream);
  launch_gemm(svbf, EP, wpadb, EP, gib, 768, M, 768, EP, bih_b, stream);
  // 4. bidirectional GRU recurrence (persistent-weight MFMA)
  gru_mfma_kernel<<<64, 512, 0, stream>>>(gif, gib, whhbf_f, whhbf_b, bhh_f, bhh_b,
                                          srep32, srepbf, hTf, hTb);
  // 5/6. doc_vec + topic_mat
  docvec_kernel<<<Bd, 512, 0, stream>>>(hTf, hTb, dvbf);
  topic_kernel<<<Bd * Td, 256, 0, stream>>>(tse, srep32, topbf);
  // 7. attention/dense GEMMs
  launch_gemm(srepbf, 512, wattT + 512, 1024, Q, 1024, M, 1024, 512, nullptr, stream);
  launch_gemm(dvbf, 512, wattT, 1024, P, 1024, Bd, 1024, 512, nullptr, stream);
  launch_gemm(topbf, 512, wattT, 1024, R, 1024, Bd * Td, 1024, 512, nullptr, stream);
  launch_gemm(srepbf, 512, wdnaT, 1024, U, Dd, M, Dd, 512, nullptr, stream);
  launch_gemm(dvbf, 512, wdnaT + 512, 1024, dvd, Dd, Bd, Dd, 512, nullptr, stream);
  launch_gemm(topbf, 512, wdnaT + 512, 1024, tvd, Dd, Bd * Td, Dd, 512, nullptr, stream);
  // 8. scores + softmax
  scores_kernel<<<M, 256, 0, stream>>>(P, R, Q, v_att, tse, dsc, tsc);
  softmax_kernel<<<Bd, 256, 0, stream>>>(dsc, tsc, dw, tw);
  // 9. fused dense head -> logits (fp32)
  final_kernel<<<M, 256, 0, stream>>>(U, dvd, tvd, dw, tw, b_dna, w_out, b_out, tse, out);
}